// Round 6
// baseline (478.022 us; speedup 1.0000x reference)
//
#include <hip/hip_runtime.h>
#include <hip/hip_bf16.h>
#include <hip/hip_cooperative_groups.h>

namespace cg = cooperative_groups;

#define Hn 512
#define Wn 512
#define HWn (512 * 512)
#define KTOP 26214

typedef __attribute__((ext_vector_type(8))) short frag_ab;  // 8 bf16
typedef __attribute__((ext_vector_type(4))) float frag_cd;  // 4 fp32

__device__ __forceinline__ float sigf(float z) { return 1.0f / (1.0f + __expf(-z)); }

__device__ __forceinline__ short f2bf(float f) {  // RNE fp32 -> bf16
  unsigned u = __float_as_uint(f);
  u += 0x7FFFu + ((u >> 16) & 1u);
  return (short)(u >> 16);
}

// ---- kernel 1: per (b,c) sums of x (color) + last-block runs weight-frag prep ----
__global__ __launch_bounds__(256) void k_means(
    const float* __restrict__ x, float* __restrict__ means, unsigned* __restrict__ doneCnt,
    const float* __restrict__ w1, const float* __restrict__ b1, const float* __restrict__ w2,
    const float* __restrict__ cw, const float* __restrict__ cb,
    short* __restrict__ w1A, short* __restrict__ w2A, float* __restrict__ colorG)
{
  const int tid = threadIdx.x;
  __shared__ int lastS;
  int bc = blockIdx.x >> 5;
  int slice = blockIdx.x & 31;
  const float4* p = (const float4*)(x + bc * HWn + slice * 8192);
  float s = 0.f;
  for (int i = tid; i < 2048; i += 256) { float4 v = p[i]; s += v.x + v.y + v.z + v.w; }
  for (int off = 32; off > 0; off >>= 1) s += __shfl_down(s, off);
  if ((tid & 63) == 0) { atomicAdd(&means[bc], s); __threadfence(); }
  __syncthreads();
  if (tid == 0) { unsigned tk = atomicAdd(doneCnt, 1u); lastS = (tk == 767); }
  __syncthreads();
  if (!lastS) return;

  // ---- prep (runs once, after all means complete) ----
  {
    int chunk = tid >> 6, lane = tid & 63;
    int m = lane & 15, q = lane >> 4;
    for (int j = 0; j < 8; ++j) {
      int k = q * 8 + j;
      float v = 0.f;
      if (k < 27) v = w1[(chunk * 16 + m) * 27 + k];
      else if (k == 27) v = b1[chunk * 16 + m];
      w1A[tid * 8 + j] = f2bf(v);
    }
  }
  for (int i = tid; i < 1152; i += 256) {
    int step = i >> 6, lane = i & 63;
    int m = lane & 15, q = lane >> 4;
    int tap = step >> 1, chb = (step & 1) * 32 + q * 8;
    for (int j = 0; j < 8; ++j) {
      int ch = chb + j;
      float v = (m < 3) ? w2[m * 576 + ch * 9 + tap] : 0.f;
      w2A[i * 8 + j] = f2bf(v);
    }
  }
  if (tid < 24) {
    int b = tid / 3, oc = tid % 3;
    float z = cb[oc];
    for (int j = 0; j < 3; ++j)
      z += (atomicAdd(&means[b * 3 + j], 0.f) * (1.0f / (float)HWn)) * cw[oc * 3 + j];
    colorG[tid] = sigf(z);
  }
}

// ---- kernel 2: fused conv1+relu+conv2+sigmoid+color+1x1conv+x_out via MFMA ----
__global__ __launch_bounds__(256, 3) void k_fused(
    const float* __restrict__ x,
    const float* __restrict__ b2, const float* __restrict__ convw, const float* __restrict__ convb,
    const short* __restrict__ w1Ag, const short* __restrict__ w2Ag,
    const float* __restrict__ colorG, float* __restrict__ out)
{
  __shared__ __align__(16) float xs[1200];              // [c][20][20] halo-2, bf16-rounded fp32
  __shared__ __align__(16) unsigned short hb[324 * 72]; // h bf16: [pt][ch], stride 72
  __shared__ float b2s[3], colorS[3], cwS[12], cbS[4];

  const int tid = threadIdx.x;
  const int wid = tid >> 6, lane = tid & 63;
  const int n = lane & 15, q = lane >> 4;
  const int tx0 = blockIdx.x * 16, ty0 = blockIdx.y * 16;
  const int b = blockIdx.z;

  for (int i = tid; i < 1200; i += 256) {
    int c = i / 400, r = i % 400, yy = r / 20, xx = r % 20;
    int gy = ty0 - 2 + yy, gx = tx0 - 2 + xx;
    float v = 0.f;
    if ((unsigned)gy < 512u && (unsigned)gx < 512u)
      v = __bfloat162float(__float2bfloat16(x[(b * 3 + c) * HWn + (gy << 9) + gx]));
    xs[i] = v;
  }
  if (tid < 3)  b2s[tid] = b2[tid];
  if (tid < 3)  colorS[tid] = colorG[b * 3 + tid];
  if (tid < 12) cwS[tid] = convw[tid];
  if (tid < 4)  cbS[tid] = convb[tid];

  frag_ab w1f[4];
#pragma unroll
  for (int ck = 0; ck < 4; ++ck) w1f[ck] = *(const frag_ab*)(w1Ag + (ck * 64 + lane) * 8);

  // conv1 im2col k-offsets as byte offsets to the HIGH u16 of the fp32 (== bf16)
  int kb[8], kf[8];  // kf: 0=read, 1=bf16(1.0), 2=zero
#pragma unroll
  for (int j = 0; j < 8; ++j) {
    int k = q * 8 + j;
    if (k < 27) { int ic = k / 9; int r = k - ic * 9; kb[j] = (ic * 400 + (r / 3) * 20 + (r % 3)) * 4 + 2; kf[j] = 0; }
    else if (k == 27) { kb[j] = 0; kf[j] = 1; }
    else { kb[j] = 0; kf[j] = 2; }
  }
  __syncthreads();

  // ---- conv1: 21 point-groups x 4 channel-chunks ----
  for (int g = wid; g < 21; g += 4) {
    int pt = g * 16 + n;
    bool ptok = pt < 324;
    int ptc = ptok ? pt : 0;
    int pty = (ptc * 3641) >> 16;  // /18 exact for pt<324
    int ptx = ptc - pty * 18;
    int baseB = (pty * 20 + ptx) * 4;
    int gy = ty0 - 1 + pty, gx = tx0 - 1 + ptx;
    bool valid = ptok && (unsigned)gy < 512u && (unsigned)gx < 512u;
    frag_ab B;
#pragma unroll
    for (int j = 0; j < 8; ++j) {
      short v;
      if (kf[j] == 0) v = *(const short*)((const char*)xs + baseB + kb[j]);
      else v = (kf[j] == 1) ? (short)0x3F80 : (short)0;
      B[j] = v;
    }
#pragma unroll
    for (int ck = 0; ck < 4; ++ck) {
      frag_cd D = {0.f, 0.f, 0.f, 0.f};
      D = __builtin_amdgcn_mfma_f32_16x16x32_bf16(w1f[ck], B, D, 0, 0, 0);
      if (ptok) {
        float h0 = valid ? fmaxf(D[0], 0.f) : 0.f;
        float h1 = valid ? fmaxf(D[1], 0.f) : 0.f;
        float h2 = valid ? fmaxf(D[2], 0.f) : 0.f;
        float h3 = valid ? fmaxf(D[3], 0.f) : 0.f;
        unsigned lo = (unsigned)(unsigned short)f2bf(h0) | ((unsigned)(unsigned short)f2bf(h1) << 16);
        unsigned hi = (unsigned)(unsigned short)f2bf(h2) | ((unsigned)(unsigned short)f2bf(h3) << 16);
        uint2 v2; v2.x = lo; v2.y = hi;
        *(uint2*)(hb + pt * 72 + ck * 16 + q * 4) = v2;
      }
    }
  }
  __syncthreads();

  // ---- conv2: 4 pixel-rows per wave, 18 K-steps, A-frags from global (L2-hot) ----
  const int pbase = wid * 4 * 18 + n;
  frag_cd acc[4];
#pragma unroll
  for (int gg = 0; gg < 4; ++gg) acc[gg] = (frag_cd){0.f, 0.f, 0.f, 0.f};

#pragma unroll 6
  for (int i = 0; i < 18; ++i) {
    frag_ab A = *(const frag_ab*)(w2Ag + (i * 64 + lane) * 8);
    int tap = i >> 1;
    int ty = (tap * 11) >> 5;         // /3 exact for tap<9
    int tx = tap - ty * 3;
    int chbyte = (i & 1) * 64 + q * 16;
    int pt0 = pbase + ty * 18 + tx;
#pragma unroll
    for (int gg = 0; gg < 4; ++gg) {
      frag_ab Bf = *(const frag_ab*)((const char*)hb + (pt0 + gg * 18) * 144 + chbyte);
      acc[gg] = __builtin_amdgcn_mfma_f32_16x16x32_bf16(A, Bf, acc[gg], 0, 0, 0);
    }
  }

  // ---- epilogue: lanes q==0 hold oc0..2 in regs 0..2 ----
  if (q == 0) {
    float c0 = colorS[0], c1 = colorS[1], c2 = colorS[2];
    float bb0 = b2s[0], bb1 = b2s[1], bb2 = b2s[2];
#pragma unroll
    for (int gg = 0; gg < 4; ++gg) {
      int py = wid * 4 + gg;
      float ih0 = c0 * sigf(acc[gg][0] + bb0);
      float ih1 = c1 * sigf(acc[gg][1] + bb1);
      float ih2 = c2 * sigf(acc[gg][2] + bb2);
      float Kv = cwS[0] * ih0 + cwS[1]  * ih1 + cwS[2]  * ih2 + cbS[0];
      float f1 = cwS[3] * ih0 + cwS[4]  * ih1 + cwS[5]  * ih2 + cbS[1];
      float f2 = cwS[6] * ih0 + cwS[7]  * ih1 + cwS[8]  * ih2 + cbS[2];
      float f3 = cwS[9] * ih0 + cwS[10] * ih1 + cwS[11] * ih2 + cbS[3];
      float xc0 = xs[0 * 400 + (py + 2) * 20 + (n + 2)];
      float xc1 = xs[1 * 400 + (py + 2) * 20 + (n + 2)];
      float xc2 = xs[2 * 400 + (py + 2) * 20 + (n + 2)];
      int oi = ((ty0 + py) << 9) + (tx0 + n);
      out[(b * 3 + 0) * HWn + oi] = Kv * xc0 - f1 + xc0;
      out[(b * 3 + 1) * HWn + oi] = Kv * xc1 - f2 + xc1;
      out[(b * 3 + 2) * HWn + oi] = Kv * xc2 - f3 + xc2;
    }
  }
}

// ---- in-block selection helpers (hist globally complete when called) ----
__device__ void sel256(const unsigned* __restrict__ h, unsigned kneed,
                       unsigned* sm, unsigned* oBin, unsigned* oAbove)
{
  const int t = threadIdx.x;
  sm[t] = h[t];
  __syncthreads();
  for (int d = 1; d < 256; d <<= 1) {
    unsigned add = (t + d < 256) ? sm[t + d] : 0u;
    __syncthreads();
    sm[t] += add;
    __syncthreads();
  }
  unsigned mine = sm[t];
  unsigned nxt = (t < 255) ? sm[t + 1] : 0u;
  if (mine >= kneed && nxt < kneed) { *oBin = (unsigned)t; *oAbove = nxt; }
  __syncthreads();
}

__device__ void sel4096(const unsigned* __restrict__ h, unsigned kneed,
                        unsigned* sm, unsigned* oBin, unsigned* oAbove)
{
  const int t = threadIdx.x;
  unsigned loc[16]; unsigned sum = 0;
#pragma unroll
  for (int i = 0; i < 16; ++i) { loc[i] = h[t * 16 + i]; sum += loc[i]; }
  sm[t] = sum;
  __syncthreads();
  for (int d = 1; d < 256; d <<= 1) {
    unsigned add = (t + d < 256) ? sm[t + d] : 0u;
    __syncthreads();
    sm[t] += add;
    __syncthreads();
  }
  unsigned mine = sm[t];
  unsigned nxt = (t < 255) ? sm[t + 1] : 0u;
  if (mine >= kneed && nxt < kneed) {
    unsigned acc = nxt;
    for (int i = 15; i >= 0; --i) {
      unsigned c = loc[i];
      if (acc + c >= kneed) { *oBin = (unsigned)(t * 16 + i); *oAbove = acc; break; }
      acc += c;
    }
  }
  __syncthreads();
}

// ---- kernel 3 (cooperative): bright -> h1 -> h12 -> h3 -> accum, one launch ----
// Block owns an 8-row strip (4096 px) of one batch; the same range in every
// phase, so bright stays hot in the local L1/L2 across phases.
__global__ __launch_bounds__(256) void k_pipeline(
    const float* __restrict__ outv, float* __restrict__ bright,
    unsigned* __restrict__ h1, unsigned* __restrict__ h12, unsigned* __restrict__ h3,
    unsigned* __restrict__ eqTaken, float* __restrict__ Asum,
    unsigned* __restrict__ doneCnt, float* __restrict__ outA)
{
  cg::grid_group grid = cg::this_grid();
  __shared__ __align__(16) float xm[10][516];
  __shared__ unsigned hh[4096];
  __shared__ unsigned sm[256];
  __shared__ unsigned sB1, sA1, sB2, sA2, sB3, sA3;
  __shared__ float red[4][3];
  __shared__ int lastA;

  const int tid = threadIdx.x;
  const int b = blockIdx.x >> 6, strip = blockIdx.x & 63;
  const int y0 = strip * 8;
  const float* op = outv + b * 3 * HWn;

  // ---- phase 1: channel-max (reflect halo) -> bright + 256-bin h1 ----
  hh[tid] = 0;
  for (int idx = tid; idx < 1280; idx += 256) {
    int r = idx >> 7, seg = idx & 127;
    int gy = y0 - 1 + r; gy = (gy < 0) ? -gy : (gy > 511 ? 1022 - gy : gy);
    int c0 = seg * 4;
    const float* rp = op + (gy << 9) + c0;
    float4 v0 = *(const float4*)rp;
    float4 v1 = *(const float4*)(rp + HWn);
    float4 v2 = *(const float4*)(rp + 2 * HWn);
    xm[r][c0 + 1] = fmaxf(v0.x, fmaxf(v1.x, v2.x));
    xm[r][c0 + 2] = fmaxf(v0.y, fmaxf(v1.y, v2.y));
    xm[r][c0 + 3] = fmaxf(v0.z, fmaxf(v1.z, v2.z));
    xm[r][c0 + 4] = fmaxf(v0.w, fmaxf(v1.w, v2.w));
  }
  if (tid < 20) {
    int r = tid >> 1, side = tid & 1;
    int gy = y0 - 1 + r; gy = (gy < 0) ? -gy : (gy > 511 ? 1022 - gy : gy);
    int gx = side ? 510 : 1;  // reflect of col 512 / col -1
    float m = fmaxf(op[(gy << 9) + gx], fmaxf(op[HWn + (gy << 9) + gx], op[2 * HWn + (gy << 9) + gx]));
    xm[r][side ? 513 : 0] = m;
  }
  __syncthreads();
  {
    const int row = tid >> 5, cl = tid & 31;
#pragma unroll 4
    for (int i = 0; i < 16; ++i) {
      int c = cl + (i << 5);   // consecutive lanes -> consecutive cols: conflict-free
      float s0 = xm[row][c]     + xm[row][c + 1]     + xm[row][c + 2];
      float s1 = xm[row + 1][c] + xm[row + 1][c + 1] + xm[row + 1][c + 2];
      float s2 = xm[row + 2][c] + xm[row + 2][c + 1] + xm[row + 2][c + 2];
      float s = (s0 + s1 + s2) * (1.f / 9.f) + xm[row + 1][c + 1] * (8.f / 9.f);
      s = fmaxf(s, 0.f);
      bright[b * HWn + ((y0 + row) << 9) + c] = s;
      atomicAdd(&hh[__float_as_uint(s) >> 24], 1u);
    }
  }
  __syncthreads();
  if (hh[tid]) atomicAdd(&h1[(b << 8) + tid], hh[tid]);
  grid.sync();

  // ---- phase 2: level-1 select + 4096-bin level-2 hist over own pixels ----
  sel256(h1 + (b << 8), KTOP, sm, &sB1, &sA1);
  for (int i = tid; i < 4096; i += 256) hh[i] = 0;
  __syncthreads();
  const float4* bp = (const float4*)(bright + b * HWn + (y0 << 9));
  const unsigned sb1 = sB1;
#pragma unroll
  for (int it = 0; it < 4; ++it) {
    float4 v = bp[it * 256 + tid];
    unsigned u0 = __float_as_uint(v.x), u1 = __float_as_uint(v.y);
    unsigned u2 = __float_as_uint(v.z), u3 = __float_as_uint(v.w);
    if ((u0 >> 24) == sb1) atomicAdd(&hh[(u0 >> 12) & 0xFFFu], 1u);
    if ((u1 >> 24) == sb1) atomicAdd(&hh[(u1 >> 12) & 0xFFFu], 1u);
    if ((u2 >> 24) == sb1) atomicAdd(&hh[(u2 >> 12) & 0xFFFu], 1u);
    if ((u3 >> 24) == sb1) atomicAdd(&hh[(u3 >> 12) & 0xFFFu], 1u);
  }
  __syncthreads();
  for (int i = tid; i < 4096; i += 256)
    if (hh[i]) atomicAdd(&h12[(b << 12) + i], hh[i]);
  grid.sync();

  // ---- phase 3: level-2 select + level-3 hist (rare hits, direct global) ----
  sel4096(h12 + (b << 12), KTOP - sA1, sm, &sB2, &sA2);
  const unsigned P20 = (sB1 << 12) | sB2;
#pragma unroll
  for (int it = 0; it < 4; ++it) {
    float4 v = bp[it * 256 + tid];
    unsigned u0 = __float_as_uint(v.x), u1 = __float_as_uint(v.y);
    unsigned u2 = __float_as_uint(v.z), u3 = __float_as_uint(v.w);
    if ((u0 >> 12) == P20) atomicAdd(&h3[(b << 12) + (u0 & 0xFFFu)], 1u);
    if ((u1 >> 12) == P20) atomicAdd(&h3[(b << 12) + (u1 & 0xFFFu)], 1u);
    if ((u2 >> 12) == P20) atomicAdd(&h3[(b << 12) + (u2 & 0xFFFu)], 1u);
    if ((u3 >> 12) == P20) atomicAdd(&h3[(b << 12) + (u3 & 0xFFFu)], 1u);
  }
  grid.sync();

  // ---- phase 4: level-3 select + accumulate picked values ----
  const unsigned kp3 = KTOP - sA1 - sA2;
  sel4096(h3 + (b << 12), kp3, sm, &sB3, &sA3);
  const unsigned T = (P20 << 12) | sB3;
  const unsigned ne = kp3 - sA3;
  float v0 = 0.f, v1 = 0.f, v2 = 0.f;
  for (int it = 0; it < 16; ++it) {
    int pix = (y0 << 9) + it * 256 + tid;
    unsigned bits = __float_as_uint(bright[b * HWn + pix]);
    bool take = bits > T;
    if (bits == T) {
      if (eqTaken[b] < ne) {
        unsigned old = atomicAdd(&eqTaken[b], 1u);
        take = old < ne;
      }
    }
    if (take) {  // reshape (C,H,W)->(H*W,C): pixel i -> flat 3i,3i+1,3i+2
      v0 += op[3 * pix];
      v1 += op[3 * pix + 1];
      v2 += op[3 * pix + 2];
    }
  }
  for (int off = 32; off > 0; off >>= 1) {
    v0 += __shfl_down(v0, off);
    v1 += __shfl_down(v1, off);
    v2 += __shfl_down(v2, off);
  }
  int w = tid >> 6;
  if ((tid & 63) == 0) { red[w][0] = v0; red[w][1] = v1; red[w][2] = v2; }
  __syncthreads();
  if (tid == 0) {
    atomicAdd(&Asum[b * 3 + 0], red[0][0] + red[1][0] + red[2][0] + red[3][0]);
    atomicAdd(&Asum[b * 3 + 1], red[0][1] + red[1][1] + red[2][1] + red[3][1]);
    atomicAdd(&Asum[b * 3 + 2], red[0][2] + red[1][2] + red[2][2] + red[3][2]);
    __threadfence();
    unsigned tk = atomicAdd(doneCnt, 1u);
    lastA = (tk == 511);
  }
  __syncthreads();
  if (lastA && tid < 24)
    outA[3 * HWn * 8 + tid] = atomicAdd(&Asum[tid], 0.f) * (1.0f / (float)KTOP);
}

extern "C" void kernel_launch(void* const* d_in, const int* in_sizes, int n_in,
                              void* d_out, int out_size, void* d_ws, size_t ws_size,
                              hipStream_t stream)
{
  const float* x     = (const float*)d_in[0];
  const float* w1    = (const float*)d_in[1];
  const float* b1    = (const float*)d_in[2];
  const float* w2    = (const float*)d_in[3];
  const float* b2    = (const float*)d_in[4];
  const float* cw    = (const float*)d_in[5];
  const float* cb    = (const float*)d_in[6];
  const float* convw = (const float*)d_in[7];
  const float* convb = (const float*)d_in[8];
  float* out = (float*)d_out;
  char* ws = (char*)d_ws;

  float*    bright    = (float*)(ws);                // 8 MB
  unsigned* h1        = (unsigned*)(ws + 8388608);   // 8192
  unsigned* h12       = (unsigned*)(ws + 8396800);   // 131072
  unsigned* h3        = (unsigned*)(ws + 8527872);   // 131072
  float*    Asum      = (float*)(ws + 8658944);      // 96
  unsigned* eqTaken   = (unsigned*)(ws + 8659040);   // 32
  float*    means     = (float*)(ws + 8659072);      // 96
  unsigned* meansDone = (unsigned*)(ws + 8659168);   // 32
  unsigned* accumDone = (unsigned*)(ws + 8659200);   // 32
  short*    w1Ag      = (short*)(ws + 8659232);      // 4096 B (16-aligned)
  short*    w2Ag      = (short*)(ws + 8663328);      // 18432 B
  float*    colorG    = (float*)(ws + 8681760);      // 96

  // zero h1, h12, h3, Asum, eqTaken, means, meansDone, accumDone
  hipMemsetAsync(ws + 8388608, 0, 8659232 - 8388608, stream);

  k_means<<<768, 256, 0, stream>>>(x, means, meansDone, w1, b1, w2, cw, cb, w1Ag, w2Ag, colorG);
  k_fused<<<dim3(32, 32, 8), 256, 0, stream>>>(x, b2, convw, convb, w1Ag, w2Ag, colorG, out);

  const float* outv = out;
  float* outA = out;
  void* args[] = { (void*)&outv, (void*)&bright, (void*)&h1, (void*)&h12, (void*)&h3,
                   (void*)&eqTaken, (void*)&Asum, (void*)&accumDone, (void*)&outA };
  hipLaunchCooperativeKernel((const void*)k_pipeline, dim3(512), dim3(256), args, 0, stream);
}

// Round 7
// 442.669 us; speedup vs baseline: 1.0799x; 1.0799x over previous
//
#include <hip/hip_runtime.h>
#include <hip/hip_bf16.h>

#define Hn 512
#define Wn 512
#define HWn (512 * 512)
#define KTOP 26214

typedef __attribute__((ext_vector_type(8))) short frag_ab;  // 8 bf16
typedef __attribute__((ext_vector_type(4))) float frag_cd;  // 4 fp32

__device__ __forceinline__ float sigf(float z) { return 1.0f / (1.0f + __expf(-z)); }

__device__ __forceinline__ short f2bf(float f) {  // RNE fp32 -> bf16
  unsigned u = __float_as_uint(f);
  u += 0x7FFFu + ((u >> 16) & 1u);
  return (short)(u >> 16);
}

__device__ __forceinline__ unsigned aload(const unsigned* p) {
  return __hip_atomic_load(p, __ATOMIC_RELAXED, __HIP_MEMORY_SCOPE_AGENT);
}

// ---- kernel 1: per (b,c) sums of x (color) + last-block runs weight-frag prep ----
__global__ __launch_bounds__(256) void k_means(
    const float* __restrict__ x, float* __restrict__ means, unsigned* __restrict__ doneCnt,
    const float* __restrict__ w1, const float* __restrict__ b1, const float* __restrict__ w2,
    const float* __restrict__ cw, const float* __restrict__ cb,
    short* __restrict__ w1A, short* __restrict__ w2A, float* __restrict__ colorG)
{
  const int tid = threadIdx.x;
  __shared__ int lastS;
  int bc = blockIdx.x >> 5;
  int slice = blockIdx.x & 31;
  const float4* p = (const float4*)(x + bc * HWn + slice * 8192);
  float s = 0.f;
  for (int i = tid; i < 2048; i += 256) { float4 v = p[i]; s += v.x + v.y + v.z + v.w; }
  for (int off = 32; off > 0; off >>= 1) s += __shfl_down(s, off);
  if ((tid & 63) == 0) { atomicAdd(&means[bc], s); __threadfence(); }
  __syncthreads();
  if (tid == 0) { unsigned tk = atomicAdd(doneCnt, 1u); lastS = (tk == 767); }
  __syncthreads();
  if (!lastS) return;

  // ---- prep (runs once, after all means complete) ----
  {
    int chunk = tid >> 6, lane = tid & 63;
    int m = lane & 15, q = lane >> 4;
    for (int j = 0; j < 8; ++j) {
      int k = q * 8 + j;
      float v = 0.f;
      if (k < 27) v = w1[(chunk * 16 + m) * 27 + k];
      else if (k == 27) v = b1[chunk * 16 + m];
      w1A[tid * 8 + j] = f2bf(v);
    }
  }
  for (int i = tid; i < 1152; i += 256) {
    int step = i >> 6, lane = i & 63;
    int m = lane & 15, q = lane >> 4;
    int tap = step >> 1, chb = (step & 1) * 32 + q * 8;
    for (int j = 0; j < 8; ++j) {
      int ch = chb + j;
      float v = (m < 3) ? w2[m * 576 + ch * 9 + tap] : 0.f;
      w2A[i * 8 + j] = f2bf(v);
    }
  }
  if (tid < 24) {
    int b = tid / 3, oc = tid % 3;
    float z = cb[oc];
    for (int j = 0; j < 3; ++j)
      z += (atomicAdd(&means[b * 3 + j], 0.f) * (1.0f / (float)HWn)) * cw[oc * 3 + j];
    colorG[tid] = sigf(z);
  }
}

// ---- kernel 2: fused conv1+relu+conv2+sigmoid+color+1x1conv+x_out via MFMA ----
__global__ __launch_bounds__(256, 3) void k_fused(
    const float* __restrict__ x,
    const float* __restrict__ b2, const float* __restrict__ convw, const float* __restrict__ convb,
    const short* __restrict__ w1Ag, const short* __restrict__ w2Ag,
    const float* __restrict__ colorG, float* __restrict__ out)
{
  __shared__ __align__(16) float xs[1200];              // [c][20][20] halo-2, bf16-rounded fp32
  __shared__ __align__(16) unsigned short hb[324 * 72]; // h bf16: [pt][ch], stride 72
  __shared__ float b2s[3], colorS[3], cwS[12], cbS[4];

  const int tid = threadIdx.x;
  const int wid = tid >> 6, lane = tid & 63;
  const int n = lane & 15, q = lane >> 4;
  const int tx0 = blockIdx.x * 16, ty0 = blockIdx.y * 16;
  const int b = blockIdx.z;

  for (int i = tid; i < 1200; i += 256) {
    int c = i / 400, r = i % 400, yy = r / 20, xx = r % 20;
    int gy = ty0 - 2 + yy, gx = tx0 - 2 + xx;
    float v = 0.f;
    if ((unsigned)gy < 512u && (unsigned)gx < 512u)
      v = __bfloat162float(__float2bfloat16(x[(b * 3 + c) * HWn + (gy << 9) + gx]));
    xs[i] = v;
  }
  if (tid < 3)  b2s[tid] = b2[tid];
  if (tid < 3)  colorS[tid] = colorG[b * 3 + tid];
  if (tid < 12) cwS[tid] = convw[tid];
  if (tid < 4)  cbS[tid] = convb[tid];

  frag_ab w1f[4];
#pragma unroll
  for (int ck = 0; ck < 4; ++ck) w1f[ck] = *(const frag_ab*)(w1Ag + (ck * 64 + lane) * 8);

  // conv1 im2col k-offsets as byte offsets to the HIGH u16 of the fp32 (== bf16)
  int kb[8], kf[8];  // kf: 0=read, 1=bf16(1.0), 2=zero
#pragma unroll
  for (int j = 0; j < 8; ++j) {
    int k = q * 8 + j;
    if (k < 27) { int ic = k / 9; int r = k - ic * 9; kb[j] = (ic * 400 + (r / 3) * 20 + (r % 3)) * 4 + 2; kf[j] = 0; }
    else if (k == 27) { kb[j] = 0; kf[j] = 1; }
    else { kb[j] = 0; kf[j] = 2; }
  }
  __syncthreads();

  // ---- conv1: 21 point-groups x 4 channel-chunks ----
  for (int g = wid; g < 21; g += 4) {
    int pt = g * 16 + n;
    bool ptok = pt < 324;
    int ptc = ptok ? pt : 0;
    int pty = (ptc * 3641) >> 16;  // /18 exact for pt<324
    int ptx = ptc - pty * 18;
    int baseB = (pty * 20 + ptx) * 4;
    int gy = ty0 - 1 + pty, gx = tx0 - 1 + ptx;
    bool valid = ptok && (unsigned)gy < 512u && (unsigned)gx < 512u;
    frag_ab B;
#pragma unroll
    for (int j = 0; j < 8; ++j) {
      short v;
      if (kf[j] == 0) v = *(const short*)((const char*)xs + baseB + kb[j]);
      else v = (kf[j] == 1) ? (short)0x3F80 : (short)0;
      B[j] = v;
    }
#pragma unroll
    for (int ck = 0; ck < 4; ++ck) {
      frag_cd D = {0.f, 0.f, 0.f, 0.f};
      D = __builtin_amdgcn_mfma_f32_16x16x32_bf16(w1f[ck], B, D, 0, 0, 0);
      if (ptok) {
        float h0 = valid ? fmaxf(D[0], 0.f) : 0.f;
        float h1 = valid ? fmaxf(D[1], 0.f) : 0.f;
        float h2 = valid ? fmaxf(D[2], 0.f) : 0.f;
        float h3 = valid ? fmaxf(D[3], 0.f) : 0.f;
        unsigned lo = (unsigned)(unsigned short)f2bf(h0) | ((unsigned)(unsigned short)f2bf(h1) << 16);
        unsigned hi = (unsigned)(unsigned short)f2bf(h2) | ((unsigned)(unsigned short)f2bf(h3) << 16);
        uint2 v2; v2.x = lo; v2.y = hi;
        *(uint2*)(hb + pt * 72 + ck * 16 + q * 4) = v2;
      }
    }
  }
  __syncthreads();

  // ---- conv2: 4 pixel-rows per wave, 18 K-steps, A-frags from global (L2-hot) ----
  const int pbase = wid * 4 * 18 + n;
  frag_cd acc[4];
#pragma unroll
  for (int gg = 0; gg < 4; ++gg) acc[gg] = (frag_cd){0.f, 0.f, 0.f, 0.f};

#pragma unroll 6
  for (int i = 0; i < 18; ++i) {
    frag_ab A = *(const frag_ab*)(w2Ag + (i * 64 + lane) * 8);
    int tap = i >> 1;
    int ty = (tap * 11) >> 5;         // /3 exact for tap<9
    int tx = tap - ty * 3;
    int chbyte = (i & 1) * 64 + q * 16;
    int pt0 = pbase + ty * 18 + tx;
#pragma unroll
    for (int gg = 0; gg < 4; ++gg) {
      frag_ab Bf = *(const frag_ab*)((const char*)hb + (pt0 + gg * 18) * 144 + chbyte);
      acc[gg] = __builtin_amdgcn_mfma_f32_16x16x32_bf16(A, Bf, acc[gg], 0, 0, 0);
    }
  }

  // ---- epilogue: lanes q==0 hold oc0..2 in regs 0..2 ----
  if (q == 0) {
    float c0 = colorS[0], c1 = colorS[1], c2 = colorS[2];
    float bb0 = b2s[0], bb1 = b2s[1], bb2 = b2s[2];
#pragma unroll
    for (int gg = 0; gg < 4; ++gg) {
      int py = wid * 4 + gg;
      float ih0 = c0 * sigf(acc[gg][0] + bb0);
      float ih1 = c1 * sigf(acc[gg][1] + bb1);
      float ih2 = c2 * sigf(acc[gg][2] + bb2);
      float Kv = cwS[0] * ih0 + cwS[1]  * ih1 + cwS[2]  * ih2 + cbS[0];
      float f1 = cwS[3] * ih0 + cwS[4]  * ih1 + cwS[5]  * ih2 + cbS[1];
      float f2 = cwS[6] * ih0 + cwS[7]  * ih1 + cwS[8]  * ih2 + cbS[2];
      float f3 = cwS[9] * ih0 + cwS[10] * ih1 + cwS[11] * ih2 + cbS[3];
      float xc0 = xs[0 * 400 + (py + 2) * 20 + (n + 2)];
      float xc1 = xs[1 * 400 + (py + 2) * 20 + (n + 2)];
      float xc2 = xs[2 * 400 + (py + 2) * 20 + (n + 2)];
      int oi = ((ty0 + py) << 9) + (tx0 + n);
      out[(b * 3 + 0) * HWn + oi] = Kv * xc0 - f1 + xc0;
      out[(b * 3 + 1) * HWn + oi] = Kv * xc1 - f2 + xc1;
      out[(b * 3 + 2) * HWn + oi] = Kv * xc2 - f3 + xc2;
    }
  }
}

// ---- per-batch soft barrier: 64 blocks arrive on a padded counter ----
__device__ __forceinline__ void softBarrier(unsigned* ctr) {
  __threadfence();
  __syncthreads();
  if (threadIdx.x == 0) {
    atomicAdd(ctr, 1u);
    while (__hip_atomic_load(ctr, __ATOMIC_ACQUIRE, __HIP_MEMORY_SCOPE_AGENT) < 64u)
      __builtin_amdgcn_s_sleep(1);
  }
  __syncthreads();
}

// ---- selection helpers reading completed global hists via agent-scope loads ----
__device__ void sel256(const unsigned* __restrict__ h, unsigned kneed,
                       unsigned* sm, unsigned* oBin, unsigned* oAbove)
{
  const int t = threadIdx.x;
  sm[t] = aload(&h[t]);
  __syncthreads();
  for (int d = 1; d < 256; d <<= 1) {
    unsigned add = (t + d < 256) ? sm[t + d] : 0u;
    __syncthreads();
    sm[t] += add;
    __syncthreads();
  }
  unsigned mine = sm[t];
  unsigned nxt = (t < 255) ? sm[t + 1] : 0u;
  if (mine >= kneed && nxt < kneed) { *oBin = (unsigned)t; *oAbove = nxt; }
  __syncthreads();
}

__device__ void sel4096(const unsigned* __restrict__ h, unsigned kneed,
                        unsigned* sm, unsigned* oBin, unsigned* oAbove)
{
  const int t = threadIdx.x;
  unsigned loc[16]; unsigned sum = 0;
#pragma unroll
  for (int i = 0; i < 16; ++i) { loc[i] = aload(&h[t * 16 + i]); sum += loc[i]; }
  sm[t] = sum;
  __syncthreads();
  for (int d = 1; d < 256; d <<= 1) {
    unsigned add = (t + d < 256) ? sm[t + d] : 0u;
    __syncthreads();
    sm[t] += add;
    __syncthreads();
  }
  unsigned mine = sm[t];
  unsigned nxt = (t < 255) ? sm[t + 1] : 0u;
  if (mine >= kneed && nxt < kneed) {
    unsigned acc = nxt;
    for (int i = 15; i >= 0; --i) {
      unsigned c = loc[i];
      if (acc + c >= kneed) { *oBin = (unsigned)(t * 16 + i); *oAbove = acc; break; }
      acc += c;
    }
  }
  __syncthreads();
}

// ---- kernel 3 (persistent, soft-barriered): bright -> h1 -> h12 -> h3 -> accum ----
// 512 blocks (64 per batch), each owns one 8-row strip in every phase.
// Cross-block data flows only through device-scope atomics; own-strip bright
// re-reads are self-coherent.
__global__ __launch_bounds__(256) void k_tail(
    const float* __restrict__ outv, float* __restrict__ bright,
    unsigned* __restrict__ h1, unsigned* __restrict__ h12, unsigned* __restrict__ h3,
    unsigned* __restrict__ eqTaken, float* __restrict__ Asum,
    unsigned* __restrict__ barCtr, unsigned* __restrict__ doneCnt, float* __restrict__ outA)
{
  __shared__ __align__(16) float xm[10][516];
  __shared__ unsigned hh[4096];
  __shared__ unsigned sm[256];
  __shared__ unsigned sB1, sA1, sB2, sA2, sB3, sA3;
  __shared__ float red[4][3];
  __shared__ int lastA;

  const int tid = threadIdx.x;
  const int b = blockIdx.x >> 6, strip = blockIdx.x & 63;
  const int y0 = strip * 8;
  const float* op = outv + b * 3 * HWn;
  unsigned* bar = barCtr + b * 48;  // 3 barriers x 64B stride

  // ---- phase 1: channel-max (reflect halo) -> bright + 256-bin h1 ----
  hh[tid] = 0;
  for (int idx = tid; idx < 1280; idx += 256) {
    int r = idx >> 7, seg = idx & 127;
    int gy = y0 - 1 + r; gy = (gy < 0) ? -gy : (gy > 511 ? 1022 - gy : gy);
    int c0 = seg * 4;
    const float* rp = op + (gy << 9) + c0;
    float4 v0 = *(const float4*)rp;
    float4 v1 = *(const float4*)(rp + HWn);
    float4 v2 = *(const float4*)(rp + 2 * HWn);
    xm[r][c0 + 1] = fmaxf(v0.x, fmaxf(v1.x, v2.x));
    xm[r][c0 + 2] = fmaxf(v0.y, fmaxf(v1.y, v2.y));
    xm[r][c0 + 3] = fmaxf(v0.z, fmaxf(v1.z, v2.z));
    xm[r][c0 + 4] = fmaxf(v0.w, fmaxf(v1.w, v2.w));
  }
  if (tid < 20) {
    int r = tid >> 1, side = tid & 1;
    int gy = y0 - 1 + r; gy = (gy < 0) ? -gy : (gy > 511 ? 1022 - gy : gy);
    int gx = side ? 510 : 1;  // reflect of col 512 / col -1
    float m = fmaxf(op[(gy << 9) + gx], fmaxf(op[HWn + (gy << 9) + gx], op[2 * HWn + (gy << 9) + gx]));
    xm[r][side ? 513 : 0] = m;
  }
  __syncthreads();
  {
    const int row = tid >> 5, cl = tid & 31;
#pragma unroll 4
    for (int i = 0; i < 16; ++i) {
      int c = cl + (i << 5);   // consecutive lanes -> consecutive cols
      float s0 = xm[row][c]     + xm[row][c + 1]     + xm[row][c + 2];
      float s1 = xm[row + 1][c] + xm[row + 1][c + 1] + xm[row + 1][c + 2];
      float s2 = xm[row + 2][c] + xm[row + 2][c + 1] + xm[row + 2][c + 2];
      float s = (s0 + s1 + s2) * (1.f / 9.f) + xm[row + 1][c + 1] * (8.f / 9.f);
      s = fmaxf(s, 0.f);
      bright[b * HWn + ((y0 + row) << 9) + c] = s;
      atomicAdd(&hh[__float_as_uint(s) >> 24], 1u);
    }
  }
  __syncthreads();
  if (hh[tid]) atomicAdd(&h1[(b << 8) + tid], hh[tid]);
  softBarrier(bar);

  // ---- phase 2: level-1 select + 4096-bin level-2 hist over own pixels ----
  sel256(h1 + (b << 8), KTOP, sm, &sB1, &sA1);
  for (int i = tid; i < 4096; i += 256) hh[i] = 0;
  __syncthreads();
  const float4* bp = (const float4*)(bright + b * HWn + (y0 << 9));
  const unsigned sb1 = sB1;
#pragma unroll
  for (int it = 0; it < 4; ++it) {
    float4 v = bp[it * 256 + tid];
    unsigned u0 = __float_as_uint(v.x), u1 = __float_as_uint(v.y);
    unsigned u2 = __float_as_uint(v.z), u3 = __float_as_uint(v.w);
    if ((u0 >> 24) == sb1) atomicAdd(&hh[(u0 >> 12) & 0xFFFu], 1u);
    if ((u1 >> 24) == sb1) atomicAdd(&hh[(u1 >> 12) & 0xFFFu], 1u);
    if ((u2 >> 24) == sb1) atomicAdd(&hh[(u2 >> 12) & 0xFFFu], 1u);
    if ((u3 >> 24) == sb1) atomicAdd(&hh[(u3 >> 12) & 0xFFFu], 1u);
  }
  __syncthreads();
  for (int i = tid; i < 4096; i += 256)
    if (hh[i]) atomicAdd(&h12[(b << 12) + i], hh[i]);
  softBarrier(bar + 16);

  // ---- phase 3: level-2 select + level-3 hist (rare hits, direct global) ----
  sel4096(h12 + (b << 12), KTOP - sA1, sm, &sB2, &sA2);
  const unsigned P20 = (sB1 << 12) | sB2;
#pragma unroll
  for (int it = 0; it < 4; ++it) {
    float4 v = bp[it * 256 + tid];
    unsigned u0 = __float_as_uint(v.x), u1 = __float_as_uint(v.y);
    unsigned u2 = __float_as_uint(v.z), u3 = __float_as_uint(v.w);
    if ((u0 >> 12) == P20) atomicAdd(&h3[(b << 12) + (u0 & 0xFFFu)], 1u);
    if ((u1 >> 12) == P20) atomicAdd(&h3[(b << 12) + (u1 & 0xFFFu)], 1u);
    if ((u2 >> 12) == P20) atomicAdd(&h3[(b << 12) + (u2 & 0xFFFu)], 1u);
    if ((u3 >> 12) == P20) atomicAdd(&h3[(b << 12) + (u3 & 0xFFFu)], 1u);
  }
  softBarrier(bar + 32);

  // ---- phase 4: level-3 select + accumulate picked values ----
  const unsigned kp3 = KTOP - sA1 - sA2;
  sel4096(h3 + (b << 12), kp3, sm, &sB3, &sA3);
  const unsigned T = (P20 << 12) | sB3;
  const unsigned ne = kp3 - sA3;
  float v0 = 0.f, v1 = 0.f, v2 = 0.f;
  for (int it = 0; it < 16; ++it) {
    int pix = (y0 << 9) + it * 256 + tid;
    unsigned bits = __float_as_uint(bright[b * HWn + pix]);
    bool take = bits > T;
    if (bits == T) {
      if (aload(&eqTaken[b * 16]) < ne) {
        unsigned old = atomicAdd(&eqTaken[b * 16], 1u);
        take = old < ne;
      }
    }
    if (take) {  // reshape (C,H,W)->(H*W,C): pixel i -> flat 3i,3i+1,3i+2
      v0 += op[3 * pix];
      v1 += op[3 * pix + 1];
      v2 += op[3 * pix + 2];
    }
  }
  for (int off = 32; off > 0; off >>= 1) {
    v0 += __shfl_down(v0, off);
    v1 += __shfl_down(v1, off);
    v2 += __shfl_down(v2, off);
  }
  int w = tid >> 6;
  if ((tid & 63) == 0) { red[w][0] = v0; red[w][1] = v1; red[w][2] = v2; }
  __syncthreads();
  if (tid == 0) {
    atomicAdd(&Asum[b * 3 + 0], red[0][0] + red[1][0] + red[2][0] + red[3][0]);
    atomicAdd(&Asum[b * 3 + 1], red[0][1] + red[1][1] + red[2][1] + red[3][1]);
    atomicAdd(&Asum[b * 3 + 2], red[0][2] + red[1][2] + red[2][2] + red[3][2]);
    __threadfence();
    unsigned tk = atomicAdd(doneCnt, 1u);
    lastA = (tk == 511);
  }
  __syncthreads();
  if (lastA && tid < 24)
    outA[3 * HWn * 8 + tid] = atomicAdd(&Asum[tid], 0.f) * (1.0f / (float)KTOP);
}

extern "C" void kernel_launch(void* const* d_in, const int* in_sizes, int n_in,
                              void* d_out, int out_size, void* d_ws, size_t ws_size,
                              hipStream_t stream)
{
  const float* x     = (const float*)d_in[0];
  const float* w1    = (const float*)d_in[1];
  const float* b1    = (const float*)d_in[2];
  const float* w2    = (const float*)d_in[3];
  const float* b2    = (const float*)d_in[4];
  const float* cw    = (const float*)d_in[5];
  const float* cb    = (const float*)d_in[6];
  const float* convw = (const float*)d_in[7];
  const float* convb = (const float*)d_in[8];
  float* out = (float*)d_out;
  char* ws = (char*)d_ws;

  float*    bright    = (float*)(ws);                // 8 MB
  unsigned* h1        = (unsigned*)(ws + 8388608);   // 8192
  unsigned* h12       = (unsigned*)(ws + 8396800);   // 131072
  unsigned* h3        = (unsigned*)(ws + 8527872);   // 131072
  float*    Asum      = (float*)(ws + 8658944);      // 96
  unsigned* eqTaken   = (unsigned*)(ws + 8659040);   // 8*16 u32 = 512 B (padded)
  float*    means     = (float*)(ws + 8659552);      // 96
  unsigned* meansDone = (unsigned*)(ws + 8659648);   // 32
  unsigned* accumDone = (unsigned*)(ws + 8659680);   // 32
  unsigned* barCtr    = (unsigned*)(ws + 8659712);   // 8 batches x 3 x 64B = 1536
  short*    w1Ag      = (short*)(ws + 8661248);      // 4096 B (16-aligned)
  short*    w2Ag      = (short*)(ws + 8665344);      // 18432 B
  float*    colorG    = (float*)(ws + 8683776);      // 96

  // zero h1..barCtr
  hipMemsetAsync(ws + 8388608, 0, 8661248 - 8388608, stream);

  k_means<<<768, 256, 0, stream>>>(x, means, meansDone, w1, b1, w2, cw, cb, w1Ag, w2Ag, colorG);
  k_fused<<<dim3(32, 32, 8), 256, 0, stream>>>(x, b2, convw, convb, w1Ag, w2Ag, colorG, out);
  k_tail<<<512, 256, 0, stream>>>(out, bright, h1, h12, h3, eqTaken, Asum, barCtr, accumDone, out);
}

// Round 8
// 303.309 us; speedup vs baseline: 1.5760x; 1.4595x over previous
//
#include <hip/hip_runtime.h>
#include <hip/hip_bf16.h>

#define Hn 512
#define Wn 512
#define HWn (512 * 512)
#define KTOP 26214

typedef __attribute__((ext_vector_type(8))) short frag_ab;  // 8 bf16
typedef __attribute__((ext_vector_type(4))) float frag_cd;  // 4 fp32

__device__ __forceinline__ float sigf(float z) { return 1.0f / (1.0f + __expf(-z)); }

__device__ __forceinline__ short f2bf(float f) {  // RNE fp32 -> bf16
  unsigned u = __float_as_uint(f);
  u += 0x7FFFu + ((u >> 16) & 1u);
  return (short)(u >> 16);
}

__device__ __forceinline__ unsigned aload(const unsigned* p) {
  return __hip_atomic_load(p, __ATOMIC_RELAXED, __HIP_MEMORY_SCOPE_AGENT);
}

// ---- kernel 1: per (b,c) sums of x (color) + last-block runs weight-frag prep ----
// No __threadfence: __syncthreads drains each thread's outstanding atomics
// (vmcnt) before the ticket add, and the last block reads means via
// device-scope atomic RMW at the coherent point.
__global__ __launch_bounds__(256) void k_means(
    const float* __restrict__ x, float* __restrict__ means, unsigned* __restrict__ doneCnt,
    const float* __restrict__ w1, const float* __restrict__ b1, const float* __restrict__ w2,
    const float* __restrict__ cw, const float* __restrict__ cb,
    short* __restrict__ w1A, short* __restrict__ w2A, float* __restrict__ colorG)
{
  const int tid = threadIdx.x;
  __shared__ int lastS;
  int bc = blockIdx.x >> 5;
  int slice = blockIdx.x & 31;
  const float4* p = (const float4*)(x + bc * HWn + slice * 8192);
  float s = 0.f;
  for (int i = tid; i < 2048; i += 256) { float4 v = p[i]; s += v.x + v.y + v.z + v.w; }
  for (int off = 32; off > 0; off >>= 1) s += __shfl_down(s, off);
  if ((tid & 63) == 0) atomicAdd(&means[bc], s);
  __syncthreads();
  if (tid == 0) {
    unsigned tk = __hip_atomic_fetch_add(doneCnt, 1u, __ATOMIC_RELAXED, __HIP_MEMORY_SCOPE_AGENT);
    lastS = (tk == 767);
  }
  __syncthreads();
  if (!lastS) return;

  // ---- prep (runs once, after all means complete) ----
  {
    int chunk = tid >> 6, lane = tid & 63;
    int m = lane & 15, q = lane >> 4;
    for (int j = 0; j < 8; ++j) {
      int k = q * 8 + j;
      float v = 0.f;
      if (k < 27) v = w1[(chunk * 16 + m) * 27 + k];
      else if (k == 27) v = b1[chunk * 16 + m];
      w1A[tid * 8 + j] = f2bf(v);
    }
  }
  for (int i = tid; i < 1152; i += 256) {
    int step = i >> 6, lane = i & 63;
    int m = lane & 15, q = lane >> 4;
    int tap = step >> 1, chb = (step & 1) * 32 + q * 8;
    for (int j = 0; j < 8; ++j) {
      int ch = chb + j;
      float v = (m < 3) ? w2[m * 576 + ch * 9 + tap] : 0.f;
      w2A[i * 8 + j] = f2bf(v);
    }
  }
  if (tid < 24) {
    int b = tid / 3, oc = tid % 3;
    float z = cb[oc];
    for (int j = 0; j < 3; ++j)
      z += (atomicAdd(&means[b * 3 + j], 0.f) * (1.0f / (float)HWn)) * cw[oc * 3 + j];
    colorG[tid] = sigf(z);
  }
}

// ---- kernel 2: fused conv1+relu+conv2+sigmoid+color+1x1conv+x_out via MFMA ----
__global__ __launch_bounds__(256, 3) void k_fused(
    const float* __restrict__ x,
    const float* __restrict__ b2, const float* __restrict__ convw, const float* __restrict__ convb,
    const short* __restrict__ w1Ag, const short* __restrict__ w2Ag,
    const float* __restrict__ colorG, float* __restrict__ out)
{
  __shared__ __align__(16) float xs[1200];              // [c][20][20] halo-2, bf16-rounded fp32
  __shared__ __align__(16) unsigned short hb[324 * 72]; // h bf16: [pt][ch], stride 72
  __shared__ float b2s[3], colorS[3], cwS[12], cbS[4];

  const int tid = threadIdx.x;
  const int wid = tid >> 6, lane = tid & 63;
  const int n = lane & 15, q = lane >> 4;
  const int tx0 = blockIdx.x * 16, ty0 = blockIdx.y * 16;
  const int b = blockIdx.z;

  for (int i = tid; i < 1200; i += 256) {
    int c = i / 400, r = i % 400, yy = r / 20, xx = r % 20;
    int gy = ty0 - 2 + yy, gx = tx0 - 2 + xx;
    float v = 0.f;
    if ((unsigned)gy < 512u && (unsigned)gx < 512u)
      v = __bfloat162float(__float2bfloat16(x[(b * 3 + c) * HWn + (gy << 9) + gx]));
    xs[i] = v;
  }
  if (tid < 3)  b2s[tid] = b2[tid];
  if (tid < 3)  colorS[tid] = colorG[b * 3 + tid];
  if (tid < 12) cwS[tid] = convw[tid];
  if (tid < 4)  cbS[tid] = convb[tid];

  frag_ab w1f[4];
#pragma unroll
  for (int ck = 0; ck < 4; ++ck) w1f[ck] = *(const frag_ab*)(w1Ag + (ck * 64 + lane) * 8);

  // conv1 im2col k-offsets as byte offsets to the HIGH u16 of the fp32 (== bf16)
  int kb[8], kf[8];  // kf: 0=read, 1=bf16(1.0), 2=zero
#pragma unroll
  for (int j = 0; j < 8; ++j) {
    int k = q * 8 + j;
    if (k < 27) { int ic = k / 9; int r = k - ic * 9; kb[j] = (ic * 400 + (r / 3) * 20 + (r % 3)) * 4 + 2; kf[j] = 0; }
    else if (k == 27) { kb[j] = 0; kf[j] = 1; }
    else { kb[j] = 0; kf[j] = 2; }
  }
  __syncthreads();

  // ---- conv1: 21 point-groups x 4 channel-chunks ----
  for (int g = wid; g < 21; g += 4) {
    int pt = g * 16 + n;
    bool ptok = pt < 324;
    int ptc = ptok ? pt : 0;
    int pty = (ptc * 3641) >> 16;  // /18 exact for pt<324
    int ptx = ptc - pty * 18;
    int baseB = (pty * 20 + ptx) * 4;
    int gy = ty0 - 1 + pty, gx = tx0 - 1 + ptx;
    bool valid = ptok && (unsigned)gy < 512u && (unsigned)gx < 512u;
    frag_ab B;
#pragma unroll
    for (int j = 0; j < 8; ++j) {
      short v;
      if (kf[j] == 0) v = *(const short*)((const char*)xs + baseB + kb[j]);
      else v = (kf[j] == 1) ? (short)0x3F80 : (short)0;
      B[j] = v;
    }
#pragma unroll
    for (int ck = 0; ck < 4; ++ck) {
      frag_cd D = {0.f, 0.f, 0.f, 0.f};
      D = __builtin_amdgcn_mfma_f32_16x16x32_bf16(w1f[ck], B, D, 0, 0, 0);
      if (ptok) {
        float h0 = valid ? fmaxf(D[0], 0.f) : 0.f;
        float h1 = valid ? fmaxf(D[1], 0.f) : 0.f;
        float h2 = valid ? fmaxf(D[2], 0.f) : 0.f;
        float h3 = valid ? fmaxf(D[3], 0.f) : 0.f;
        unsigned lo = (unsigned)(unsigned short)f2bf(h0) | ((unsigned)(unsigned short)f2bf(h1) << 16);
        unsigned hi = (unsigned)(unsigned short)f2bf(h2) | ((unsigned)(unsigned short)f2bf(h3) << 16);
        uint2 v2; v2.x = lo; v2.y = hi;
        *(uint2*)(hb + pt * 72 + ck * 16 + q * 4) = v2;
      }
    }
  }
  __syncthreads();

  // ---- conv2: 4 pixel-rows per wave, 18 K-steps, A-frags from global (L2-hot) ----
  const int pbase = wid * 4 * 18 + n;
  frag_cd acc[4];
#pragma unroll
  for (int gg = 0; gg < 4; ++gg) acc[gg] = (frag_cd){0.f, 0.f, 0.f, 0.f};

#pragma unroll 6
  for (int i = 0; i < 18; ++i) {
    frag_ab A = *(const frag_ab*)(w2Ag + (i * 64 + lane) * 8);
    int tap = i >> 1;
    int ty = (tap * 11) >> 5;         // /3 exact for tap<9
    int tx = tap - ty * 3;
    int chbyte = (i & 1) * 64 + q * 16;
    int pt0 = pbase + ty * 18 + tx;
#pragma unroll
    for (int gg = 0; gg < 4; ++gg) {
      frag_ab Bf = *(const frag_ab*)((const char*)hb + (pt0 + gg * 18) * 144 + chbyte);
      acc[gg] = __builtin_amdgcn_mfma_f32_16x16x32_bf16(A, Bf, acc[gg], 0, 0, 0);
    }
  }

  // ---- epilogue: lanes q==0 hold oc0..2 in regs 0..2 ----
  if (q == 0) {
    float c0 = colorS[0], c1 = colorS[1], c2 = colorS[2];
    float bb0 = b2s[0], bb1 = b2s[1], bb2 = b2s[2];
#pragma unroll
    for (int gg = 0; gg < 4; ++gg) {
      int py = wid * 4 + gg;
      float ih0 = c0 * sigf(acc[gg][0] + bb0);
      float ih1 = c1 * sigf(acc[gg][1] + bb1);
      float ih2 = c2 * sigf(acc[gg][2] + bb2);
      float Kv = cwS[0] * ih0 + cwS[1]  * ih1 + cwS[2]  * ih2 + cbS[0];
      float f1 = cwS[3] * ih0 + cwS[4]  * ih1 + cwS[5]  * ih2 + cbS[1];
      float f2 = cwS[6] * ih0 + cwS[7]  * ih1 + cwS[8]  * ih2 + cbS[2];
      float f3 = cwS[9] * ih0 + cwS[10] * ih1 + cwS[11] * ih2 + cbS[3];
      float xc0 = xs[0 * 400 + (py + 2) * 20 + (n + 2)];
      float xc1 = xs[1 * 400 + (py + 2) * 20 + (n + 2)];
      float xc2 = xs[2 * 400 + (py + 2) * 20 + (n + 2)];
      int oi = ((ty0 + py) << 9) + (tx0 + n);
      out[(b * 3 + 0) * HWn + oi] = Kv * xc0 - f1 + xc0;
      out[(b * 3 + 1) * HWn + oi] = Kv * xc1 - f2 + xc1;
      out[(b * 3 + 2) * HWn + oi] = Kv * xc2 - f3 + xc2;
    }
  }
}

// ---- per-batch soft barrier, NO cache-wide fences ----
// Correctness: cross-block data flows only through device-scope atomics
// (h1/h12/h3/Asum/eqTaken), which operate at the shared coherent point and are
// read back with agent-scope atomic loads (aload). __syncthreads drains each
// thread's outstanding vmem (so its atomics retired) before thread 0 arrives.
__device__ __forceinline__ void softBarrier(unsigned* ctr) {
  __syncthreads();
  if (threadIdx.x == 0) {
    __hip_atomic_fetch_add(ctr, 1u, __ATOMIC_RELAXED, __HIP_MEMORY_SCOPE_AGENT);
    while (__hip_atomic_load(ctr, __ATOMIC_RELAXED, __HIP_MEMORY_SCOPE_AGENT) < 64u)
      __builtin_amdgcn_s_sleep(2);
  }
  __syncthreads();
}

// ---- selection helpers reading completed global hists via agent-scope loads ----
__device__ void sel256(const unsigned* __restrict__ h, unsigned kneed,
                       unsigned* sm, unsigned* oBin, unsigned* oAbove)
{
  const int t = threadIdx.x;
  sm[t] = aload(&h[t]);
  __syncthreads();
  for (int d = 1; d < 256; d <<= 1) {
    unsigned add = (t + d < 256) ? sm[t + d] : 0u;
    __syncthreads();
    sm[t] += add;
    __syncthreads();
  }
  unsigned mine = sm[t];
  unsigned nxt = (t < 255) ? sm[t + 1] : 0u;
  if (mine >= kneed && nxt < kneed) { *oBin = (unsigned)t; *oAbove = nxt; }
  __syncthreads();
}

__device__ void sel4096(const unsigned* __restrict__ h, unsigned kneed,
                        unsigned* sm, unsigned* oBin, unsigned* oAbove)
{
  const int t = threadIdx.x;
  unsigned loc[16]; unsigned sum = 0;
#pragma unroll
  for (int i = 0; i < 16; ++i) { loc[i] = aload(&h[t * 16 + i]); sum += loc[i]; }
  sm[t] = sum;
  __syncthreads();
  for (int d = 1; d < 256; d <<= 1) {
    unsigned add = (t + d < 256) ? sm[t + d] : 0u;
    __syncthreads();
    sm[t] += add;
    __syncthreads();
  }
  unsigned mine = sm[t];
  unsigned nxt = (t < 255) ? sm[t + 1] : 0u;
  if (mine >= kneed && nxt < kneed) {
    unsigned acc = nxt;
    for (int i = 15; i >= 0; --i) {
      unsigned c = loc[i];
      if (acc + c >= kneed) { *oBin = (unsigned)(t * 16 + i); *oAbove = acc; break; }
      acc += c;
    }
  }
  __syncthreads();
}

// ---- kernel 3 (persistent, soft-barriered): bright -> h1 -> h12 -> h3 -> accum ----
__global__ __launch_bounds__(256) void k_tail(
    const float* __restrict__ outv, float* __restrict__ bright,
    unsigned* __restrict__ h1, unsigned* __restrict__ h12, unsigned* __restrict__ h3,
    unsigned* __restrict__ eqTaken, float* __restrict__ Asum,
    unsigned* __restrict__ barCtr, unsigned* __restrict__ doneCnt, float* __restrict__ outA)
{
  __shared__ __align__(16) float xm[10][516];
  __shared__ unsigned hh[4096];
  __shared__ unsigned sm[256];
  __shared__ unsigned sB1, sA1, sB2, sA2, sB3, sA3;
  __shared__ float red[4][3];
  __shared__ int lastA;

  const int tid = threadIdx.x;
  const int b = blockIdx.x >> 6, strip = blockIdx.x & 63;
  const int y0 = strip * 8;
  const float* op = outv + b * 3 * HWn;
  unsigned* bar = barCtr + b * 48;  // 3 barriers x 64B stride

  // ---- phase 1: channel-max (reflect halo) -> bright + 256-bin h1 ----
  hh[tid] = 0;
  for (int idx = tid; idx < 1280; idx += 256) {
    int r = idx >> 7, seg = idx & 127;
    int gy = y0 - 1 + r; gy = (gy < 0) ? -gy : (gy > 511 ? 1022 - gy : gy);
    int c0 = seg * 4;
    const float* rp = op + (gy << 9) + c0;
    float4 v0 = *(const float4*)rp;
    float4 v1 = *(const float4*)(rp + HWn);
    float4 v2 = *(const float4*)(rp + 2 * HWn);
    xm[r][c0 + 1] = fmaxf(v0.x, fmaxf(v1.x, v2.x));
    xm[r][c0 + 2] = fmaxf(v0.y, fmaxf(v1.y, v2.y));
    xm[r][c0 + 3] = fmaxf(v0.z, fmaxf(v1.z, v2.z));
    xm[r][c0 + 4] = fmaxf(v0.w, fmaxf(v1.w, v2.w));
  }
  if (tid < 20) {
    int r = tid >> 1, side = tid & 1;
    int gy = y0 - 1 + r; gy = (gy < 0) ? -gy : (gy > 511 ? 1022 - gy : gy);
    int gx = side ? 510 : 1;  // reflect of col 512 / col -1
    float m = fmaxf(op[(gy << 9) + gx], fmaxf(op[HWn + (gy << 9) + gx], op[2 * HWn + (gy << 9) + gx]));
    xm[r][side ? 513 : 0] = m;
  }
  __syncthreads();
  {
    const int row = tid >> 5, cl = tid & 31;
#pragma unroll 4
    for (int i = 0; i < 16; ++i) {
      int c = cl + (i << 5);   // consecutive lanes -> consecutive cols
      float s0 = xm[row][c]     + xm[row][c + 1]     + xm[row][c + 2];
      float s1 = xm[row + 1][c] + xm[row + 1][c + 1] + xm[row + 1][c + 2];
      float s2 = xm[row + 2][c] + xm[row + 2][c + 1] + xm[row + 2][c + 2];
      float s = (s0 + s1 + s2) * (1.f / 9.f) + xm[row + 1][c + 1] * (8.f / 9.f);
      s = fmaxf(s, 0.f);
      bright[b * HWn + ((y0 + row) << 9) + c] = s;
      atomicAdd(&hh[__float_as_uint(s) >> 24], 1u);
    }
  }
  __syncthreads();
  if (hh[tid]) atomicAdd(&h1[(b << 8) + tid], hh[tid]);
  softBarrier(bar);

  // ---- phase 2: level-1 select + 4096-bin level-2 hist over own pixels ----
  sel256(h1 + (b << 8), KTOP, sm, &sB1, &sA1);
  for (int i = tid; i < 4096; i += 256) hh[i] = 0;
  __syncthreads();
  const float4* bp = (const float4*)(bright + b * HWn + (y0 << 9));
  const unsigned sb1 = sB1;
#pragma unroll
  for (int it = 0; it < 4; ++it) {
    float4 v = bp[it * 256 + tid];
    unsigned u0 = __float_as_uint(v.x), u1 = __float_as_uint(v.y);
    unsigned u2 = __float_as_uint(v.z), u3 = __float_as_uint(v.w);
    if ((u0 >> 24) == sb1) atomicAdd(&hh[(u0 >> 12) & 0xFFFu], 1u);
    if ((u1 >> 24) == sb1) atomicAdd(&hh[(u1 >> 12) & 0xFFFu], 1u);
    if ((u2 >> 24) == sb1) atomicAdd(&hh[(u2 >> 12) & 0xFFFu], 1u);
    if ((u3 >> 24) == sb1) atomicAdd(&hh[(u3 >> 12) & 0xFFFu], 1u);
  }
  __syncthreads();
  for (int i = tid; i < 4096; i += 256)
    if (hh[i]) atomicAdd(&h12[(b << 12) + i], hh[i]);
  softBarrier(bar + 16);

  // ---- phase 3: level-2 select + level-3 hist (rare hits, direct global) ----
  sel4096(h12 + (b << 12), KTOP - sA1, sm, &sB2, &sA2);
  const unsigned P20 = (sB1 << 12) | sB2;
#pragma unroll
  for (int it = 0; it < 4; ++it) {
    float4 v = bp[it * 256 + tid];
    unsigned u0 = __float_as_uint(v.x), u1 = __float_as_uint(v.y);
    unsigned u2 = __float_as_uint(v.z), u3 = __float_as_uint(v.w);
    if ((u0 >> 12) == P20) atomicAdd(&h3[(b << 12) + (u0 & 0xFFFu)], 1u);
    if ((u1 >> 12) == P20) atomicAdd(&h3[(b << 12) + (u1 & 0xFFFu)], 1u);
    if ((u2 >> 12) == P20) atomicAdd(&h3[(b << 12) + (u2 & 0xFFFu)], 1u);
    if ((u3 >> 12) == P20) atomicAdd(&h3[(b << 12) + (u3 & 0xFFFu)], 1u);
  }
  softBarrier(bar + 32);

  // ---- phase 4: level-3 select + accumulate picked values ----
  const unsigned kp3 = KTOP - sA1 - sA2;
  sel4096(h3 + (b << 12), kp3, sm, &sB3, &sA3);
  const unsigned T = (P20 << 12) | sB3;
  const unsigned ne = kp3 - sA3;
  float v0 = 0.f, v1 = 0.f, v2 = 0.f;
  for (int it = 0; it < 16; ++it) {
    int pix = (y0 << 9) + it * 256 + tid;
    unsigned bits = __float_as_uint(bright[b * HWn + pix]);
    bool take = bits > T;
    if (bits == T) {
      if (aload(&eqTaken[b * 16]) < ne) {
        unsigned old = atomicAdd(&eqTaken[b * 16], 1u);
        take = old < ne;
      }
    }
    if (take) {  // reshape (C,H,W)->(H*W,C): pixel i -> flat 3i,3i+1,3i+2
      v0 += op[3 * pix];
      v1 += op[3 * pix + 1];
      v2 += op[3 * pix + 2];
    }
  }
  for (int off = 32; off > 0; off >>= 1) {
    v0 += __shfl_down(v0, off);
    v1 += __shfl_down(v1, off);
    v2 += __shfl_down(v2, off);
  }
  int w = tid >> 6;
  if ((tid & 63) == 0) { red[w][0] = v0; red[w][1] = v1; red[w][2] = v2; }
  __syncthreads();
  if (tid == 0) {
    atomicAdd(&Asum[b * 3 + 0], red[0][0] + red[1][0] + red[2][0] + red[3][0]);
    atomicAdd(&Asum[b * 3 + 1], red[0][1] + red[1][1] + red[2][1] + red[3][1]);
    atomicAdd(&Asum[b * 3 + 2], red[0][2] + red[1][2] + red[2][2] + red[3][2]);
  }
  __syncthreads();
  if (tid == 0) {
    unsigned tk = __hip_atomic_fetch_add(doneCnt, 1u, __ATOMIC_RELAXED, __HIP_MEMORY_SCOPE_AGENT);
    lastA = (tk == 511);
  }
  __syncthreads();
  if (lastA && tid < 24)
    outA[3 * HWn * 8 + tid] = atomicAdd(&Asum[tid], 0.f) * (1.0f / (float)KTOP);
}

extern "C" void kernel_launch(void* const* d_in, const int* in_sizes, int n_in,
                              void* d_out, int out_size, void* d_ws, size_t ws_size,
                              hipStream_t stream)
{
  const float* x     = (const float*)d_in[0];
  const float* w1    = (const float*)d_in[1];
  const float* b1    = (const float*)d_in[2];
  const float* w2    = (const float*)d_in[3];
  const float* b2    = (const float*)d_in[4];
  const float* cw    = (const float*)d_in[5];
  const float* cb    = (const float*)d_in[6];
  const float* convw = (const float*)d_in[7];
  const float* convb = (const float*)d_in[8];
  float* out = (float*)d_out;
  char* ws = (char*)d_ws;

  float*    bright    = (float*)(ws);                // 8 MB
  unsigned* h1        = (unsigned*)(ws + 8388608);   // 8192
  unsigned* h12       = (unsigned*)(ws + 8396800);   // 131072
  unsigned* h3        = (unsigned*)(ws + 8527872);   // 131072
  float*    Asum      = (float*)(ws + 8658944);      // 96
  unsigned* eqTaken   = (unsigned*)(ws + 8659040);   // 8*16 u32 = 512 B (padded)
  float*    means     = (float*)(ws + 8659552);      // 96
  unsigned* meansDone = (unsigned*)(ws + 8659648);   // 32
  unsigned* accumDone = (unsigned*)(ws + 8659680);   // 32
  unsigned* barCtr    = (unsigned*)(ws + 8659712);   // 8 batches x 3 x 64B = 1536
  short*    w1Ag      = (short*)(ws + 8661248);      // 4096 B (16-aligned)
  short*    w2Ag      = (short*)(ws + 8665344);      // 18432 B
  float*    colorG    = (float*)(ws + 8683776);      // 96

  // zero h1..barCtr
  hipMemsetAsync(ws + 8388608, 0, 8661248 - 8388608, stream);

  k_means<<<768, 256, 0, stream>>>(x, means, meansDone, w1, b1, w2, cw, cb, w1Ag, w2Ag, colorG);
  k_fused<<<dim3(32, 32, 8), 256, 0, stream>>>(x, b2, convw, convb, w1Ag, w2Ag, colorG, out);
  k_tail<<<512, 256, 0, stream>>>(out, bright, h1, h12, h3, eqTaken, Asum, barCtr, accumDone, out);
}